// Round 1
// baseline (273.993 us; speedup 1.0000x reference)
//
#include <hip/hip_runtime.h>

// Separable 5x5 Gaussian blur, sigma=1.1, BORDER_REFLECT_101, NHWC fp32.
// Shape: (64, 384, 512, 3). Row = 512*3 = 1536 floats = 384 float4 (coalesces
// perfectly). One block per (batch, 8-row tile): vertical blur global->LDS,
// horizontal blur LDS->global. Fused => HBM traffic ~= 1 read + 1 write.

#define BN 64
#define HN 384
#define WN 512
#define CN 3
#define ROWF (WN * CN)              // 1536 floats per row
#define ROWQ (ROWF / 4)             // 384 float4 per row
#define TH 8                        // rows per block tile
#define NTILES (HN / TH)            // 48 tiles per image
#define NTHREADS 256
#define ITERS ((TH * ROWQ) / NTHREADS)  // 12

// Gaussian taps for ksize=5, sigma=1.1 (precomputed, normalized):
#define CW0 0.07076630f
#define CW1 0.24446040f
#define CW2 0.36954650f

__global__ __launch_bounds__(NTHREADS) void gauss_blur_fused(
        const float* __restrict__ x, float* __restrict__ out) {
    // 48 KB: vertical-blur result for TH full-width rows -> 3 blocks/CU by LDS
    __shared__ float v[TH * ROWF];

    const int tile = blockIdx.x;
    const int b    = tile / NTILES;
    const int h0   = (tile - b * NTILES) * TH;
    const float* __restrict__ xb = x + (size_t)b * HN * ROWF;
    float* __restrict__ ob = out + (size_t)b * HN * ROWF + (size_t)h0 * ROWF;

    // ---- vertical pass: v[r][*] = sum_k w[k] * x[reflect101(h0+r+k-2)][*]
    for (int i = 0; i < ITERS; ++i) {
        int idx = threadIdx.x + i * NTHREADS;   // float4 index within tile
        int r = idx / ROWQ;
        int q = idx - r * ROWQ;
        int h = h0 + r;
        float4 acc = make_float4(0.f, 0.f, 0.f, 0.f);
#pragma unroll
        for (int k = 0; k < 5; ++k) {
            int hs = h + k - 2;
            hs = hs < 0 ? -hs : hs;                 // reflect101 low
            hs = hs >= HN ? 2 * HN - 2 - hs : hs;   // reflect101 high
            float wk = (k == 2) ? CW2 : ((k == 1 || k == 3) ? CW1 : CW0);
            const float4 t = ((const float4*)(xb + (size_t)hs * ROWF))[q];
            acc.x += wk * t.x;
            acc.y += wk * t.y;
            acc.z += wk * t.z;
            acc.w += wk * t.w;
        }
        ((float4*)v)[idx] = acc;
    }
    __syncthreads();

    // ---- horizontal pass from LDS
    for (int i = 0; i < ITERS; ++i) {
        int idx = threadIdx.x + i * NTHREADS;
        int r = idx / ROWQ;
        int q = idx - r * ROWQ;
        const float* vr = v + r * ROWF;
        float4 res;
        if (q >= 2 && q < ROWQ - 2) {
            // Fast path: output pixels 2..509 -> no horizontal reflect needed.
            // Window: floats 4q-8 .. 4q+11 (20 floats via 5 aligned ds_read_b128)
            float wnd[20];
#pragma unroll
            for (int j = 0; j < 5; ++j) {
                float4 t = ((const float4*)vr)[q - 2 + j];
                wnd[4 * j + 0] = t.x;
                wnd[4 * j + 1] = t.y;
                wnd[4 * j + 2] = t.z;
                wnd[4 * j + 3] = t.w;
            }
            // out float e = 4q+j; needs v[e + 3*(k-2)] -> wnd[j + 3k + 2]
#pragma unroll
            for (int j = 0; j < 4; ++j) {
                ((float*)&res)[j] =
                    CW0 * (wnd[j + 2] + wnd[j + 14]) +
                    CW1 * (wnd[j + 5] + wnd[j + 11]) +
                    CW2 * wnd[j + 8];
            }
        } else {
            // Slow path (q in {0,1,382,383}): per-pixel reflect101 in W.
#pragma unroll
            for (int j = 0; j < 4; ++j) {
                int e  = 4 * q + j;
                int wp = e / 3;
                int c  = e - wp * 3;
                float s = 0.f;
#pragma unroll
                for (int k = 0; k < 5; ++k) {
                    int ws = wp + k - 2;
                    ws = ws < 0 ? -ws : ws;
                    ws = ws >= WN ? 2 * WN - 2 - ws : ws;
                    float wk = (k == 2) ? CW2 : ((k == 1 || k == 3) ? CW1 : CW0);
                    s += wk * vr[ws * 3 + c];
                }
                ((float*)&res)[j] = s;
            }
        }
        ((float4*)ob)[idx] = res;
    }
}

extern "C" void kernel_launch(void* const* d_in, const int* in_sizes, int n_in,
                              void* d_out, int out_size, void* d_ws, size_t ws_size,
                              hipStream_t stream) {
    const float* x = (const float*)d_in[0];
    float* out = (float*)d_out;
    gauss_blur_fused<<<dim3(BN * NTILES), dim3(NTHREADS), 0, stream>>>(x, out);
}

// Round 2
// 265.124 us; speedup vs baseline: 1.0335x; 1.0335x over previous
//
#include <hip/hip_runtime.h>

// Separable 5x5 Gaussian blur, sigma=1.1, BORDER_REFLECT_101, NHWC fp32.
// Shape: (64, 384, 512, 3). Row = 512*3 = 1536 floats = 384 float4.
// One block per (batch, 4-row tile); 384 threads = one thread per float4
// column. Vertical: 8 independent coalesced float4 loads (sliding window)
// -> 4 vertical sums -> 24 KB LDS. Horizontal: 5 ds_read_b128 per output.
// LDS=24KB + 6 waves/block + <=64 VGPR => ~30/32 waves per CU (latency fix
// vs R0's 48KB/9-wave config which ran 103us at 32% HBM).

#define BN 64
#define HN 384
#define WN 512
#define CN 3
#define ROWF (WN * CN)              // 1536 floats per row
#define ROWQ (ROWF / 4)             // 384 float4 per row
#define TH 4                        // rows per block tile
#define NTILES (HN / TH)            // 96 tiles per image
#define NT 384                      // one thread per float4 column

// Gaussian taps for ksize=5, sigma=1.1 (precomputed, normalized):
#define CW0 0.07076630f
#define CW1 0.24446040f
#define CW2 0.36954650f

__global__ __launch_bounds__(NT, 8) void gauss_blur_fused(
        const float* __restrict__ x, float* __restrict__ out) {
    __shared__ float v[TH * ROWF];   // 24 KB vertical-blur tile

    const int tile = blockIdx.x;
    const int b    = tile / NTILES;
    const int h0   = (tile - b * NTILES) * TH;
    const float* __restrict__ xb = x + (size_t)b * HN * ROWF;
    float* __restrict__ ob = out + (size_t)b * HN * ROWF + (size_t)h0 * ROWF;

    const int q = threadIdx.x;       // float4 column index, 0..383

    // ---- vertical pass: load 8 rows (all loads independent -> in flight)
    float4 rowv[TH + 4];
#pragma unroll
    for (int i = 0; i < TH + 4; ++i) {
        int hs = h0 + i - 2;
        hs = hs < 0 ? -hs : hs;                 // reflect101 low (wave-uniform)
        hs = hs >= HN ? 2 * HN - 2 - hs : hs;   // reflect101 high
        rowv[i] = ((const float4*)(xb + (size_t)hs * ROWF))[q];
    }
#pragma unroll
    for (int r = 0; r < TH; ++r) {
        float4 a;
        a.x = CW0 * (rowv[r].x + rowv[r + 4].x) +
              CW1 * (rowv[r + 1].x + rowv[r + 3].x) + CW2 * rowv[r + 2].x;
        a.y = CW0 * (rowv[r].y + rowv[r + 4].y) +
              CW1 * (rowv[r + 1].y + rowv[r + 3].y) + CW2 * rowv[r + 2].y;
        a.z = CW0 * (rowv[r].z + rowv[r + 4].z) +
              CW1 * (rowv[r + 1].z + rowv[r + 3].z) + CW2 * rowv[r + 2].z;
        a.w = CW0 * (rowv[r].w + rowv[r + 4].w) +
              CW1 * (rowv[r + 1].w + rowv[r + 3].w) + CW2 * rowv[r + 2].w;
        ((float4*)v)[r * ROWQ + q] = a;
    }
    __syncthreads();

    // ---- horizontal pass: thread computes outputs (r, q) for r = 0..TH-1
    if (q >= 2 && q < ROWQ - 2) {
#pragma unroll
        for (int r = 0; r < TH; ++r) {
            const float* vr = v + r * ROWF;
            float wnd[20];
#pragma unroll
            for (int j = 0; j < 5; ++j) {
                float4 t = ((const float4*)vr)[q - 2 + j];
                wnd[4 * j + 0] = t.x;
                wnd[4 * j + 1] = t.y;
                wnd[4 * j + 2] = t.z;
                wnd[4 * j + 3] = t.w;
            }
            float4 res;
#pragma unroll
            for (int j = 0; j < 4; ++j) {
                ((float*)&res)[j] =
                    CW0 * (wnd[j + 2] + wnd[j + 14]) +
                    CW1 * (wnd[j + 5] + wnd[j + 11]) +
                    CW2 * wnd[j + 8];
            }
            ((float4*)ob)[r * ROWQ + q] = res;
        }
    } else {
        // Slow path (q in {0,1,382,383}): per-pixel reflect101 in W.
#pragma unroll
        for (int r = 0; r < TH; ++r) {
            const float* vr = v + r * ROWF;
            float4 res;
#pragma unroll
            for (int j = 0; j < 4; ++j) {
                int e  = 4 * q + j;
                int wp = e / 3;
                int c  = e - wp * 3;
                float s = 0.f;
#pragma unroll
                for (int k = 0; k < 5; ++k) {
                    int ws = wp + k - 2;
                    ws = ws < 0 ? -ws : ws;
                    ws = ws >= WN ? 2 * WN - 2 - ws : ws;
                    float wk = (k == 2) ? CW2 : ((k == 1 || k == 3) ? CW1 : CW0);
                    s += wk * vr[ws * 3 + c];
                }
                ((float*)&res)[j] = s;
            }
            ((float4*)ob)[r * ROWQ + q] = res;
        }
    }
}

extern "C" void kernel_launch(void* const* d_in, const int* in_sizes, int n_in,
                              void* d_out, int out_size, void* d_ws, size_t ws_size,
                              hipStream_t stream) {
    const float* x = (const float*)d_in[0];
    float* out = (float*)d_out;
    gauss_blur_fused<<<dim3(BN * NTILES), dim3(NT), 0, stream>>>(x, out);
}

// Round 4
// 258.253 us; speedup vs baseline: 1.0609x; 1.0266x over previous
//
#include <hip/hip_runtime.h>

// Separable 5x5 Gaussian blur, sigma=1.1, BORDER_REFLECT_101, NHWC fp32.
// Shape: (64, 384, 512, 3). Row = 512*3 = 1536 floats = 384 float4.
// One block per (batch, 4-row tile); 384 threads = one thread per float4
// column. Vertical: 8 independent coalesced float4 loads (sliding window)
// -> 4 vertical sums -> padded LDS rows (2 float4 pad each side holding the
// reflect101 edge floats) -> fully uniform horizontal pass (no divergent
// edge path). Nontemporal output stores keep the input L3-resident; XCD
// swizzle gives each XCD contiguous tiles so halo rows hit its own L2.

#define BN 64
#define HN 384
#define WN 512
#define CN 3
#define ROWF (WN * CN)              // 1536 floats per row
#define ROWQ (ROWF / 4)             // 384 float4 per row
#define TH 4                        // rows per block tile
#define NTILES (HN / TH)            // 96 tiles per image
#define NT 384                      // one thread per float4 column
#define NBLK (BN * NTILES)          // 6144 blocks

#define PADQ 2                      // float4 pad each side of an LDS row
#define LROWQ (ROWQ + 2 * PADQ)     // 388 float4
#define LROWF (LROWQ * 4)           // 1552 floats

// Gaussian taps for ksize=5, sigma=1.1 (precomputed, normalized):
#define CW0 0.07076630f
#define CW1 0.24446040f
#define CW2 0.36954650f

// Native clang vector type: __builtin_nontemporal_store requires it
// (HIP's float4 is a class and is rejected).
typedef float vfloat4 __attribute__((ext_vector_type(4)));

__global__ __launch_bounds__(NT, 6) void gauss_blur_fused(
        const float* __restrict__ x, float* __restrict__ out) {
    __shared__ float v[TH * LROWF];   // 24832 B padded vertical-blur tile

    // XCD-contiguous tile swizzle: XCD k (blockIdx%8) gets tiles
    // [k*768, (k+1)*768) in linear order -> adjacent tiles (shared halo
    // rows) run on the same XCD's L2.
    const int bid  = blockIdx.x;
    const int tile = (bid & 7) * (NBLK >> 3) + (bid >> 3);
    const int b    = tile / NTILES;
    const int h0   = (tile - b * NTILES) * TH;
    const float* __restrict__ xb = x + (size_t)b * HN * ROWF;
    float* __restrict__ ob = out + (size_t)b * HN * ROWF + (size_t)h0 * ROWF;

    const int q = threadIdx.x;       // float4 column index, 0..383

    // ---- vertical pass: 8 independent coalesced loads, then 4 sums
    float4 rowv[TH + 4];
#pragma unroll
    for (int i = 0; i < TH + 4; ++i) {
        int hs = h0 + i - 2;
        hs = hs < 0 ? -hs : hs;                 // reflect101 low (wave-uniform)
        hs = hs >= HN ? 2 * HN - 2 - hs : hs;   // reflect101 high
        rowv[i] = ((const float4*)(xb + (size_t)hs * ROWF))[q];
    }
#pragma unroll
    for (int r = 0; r < TH; ++r) {
        float4 a;
        a.x = CW0 * (rowv[r].x + rowv[r + 4].x) +
              CW1 * (rowv[r + 1].x + rowv[r + 3].x) + CW2 * rowv[r + 2].x;
        a.y = CW0 * (rowv[r].y + rowv[r + 4].y) +
              CW1 * (rowv[r + 1].y + rowv[r + 3].y) + CW2 * rowv[r + 2].y;
        a.z = CW0 * (rowv[r].z + rowv[r + 4].z) +
              CW1 * (rowv[r + 1].z + rowv[r + 3].z) + CW2 * rowv[r + 2].z;
        a.w = CW0 * (rowv[r].w + rowv[r + 4].w) +
              CW1 * (rowv[r + 1].w + rowv[r + 3].w) + CW2 * rowv[r + 2].w;
        ((float4*)(v + r * LROWF))[PADQ + q] = a;
    }
    __syncthreads();

    // ---- fill reflect101 pads: 12 floats per row (6 left, 6 right).
    // Interior float F lives at vr[F] where vr = row base + 8 floats.
    if (threadIdx.x < TH * 12) {
        int r = threadIdx.x / 12;
        int p = threadIdx.x - r * 12;
        float* vr = v + r * LROWF + 4 * PADQ;
        int dst, src;
        if (p < 6) {               // F = p-6 in {-6..-1}: pixels -2,-1
            dst = p - 6;
            src = (p < 3) ? 6 + p : p;          // {6,7,8,3,4,5}
        } else {                   // F = 1536+(p-6): pixels 512,513
            int pp = p - 6;
            dst = 1536 + pp;
            src = (pp < 3) ? 1530 + pp : 1524 + pp;
        }
        vr[dst] = vr[src];
    }
    __syncthreads();

    // ---- horizontal pass: uniform for all q (pads hold reflected data)
#pragma unroll
    for (int r = 0; r < TH; ++r) {
        const float* vr = v + r * LROWF;   // padded row base
        float wnd[20];                     // padded floats 4q .. 4q+19
#pragma unroll
        for (int j = 0; j < 5; ++j) {
            float4 t = ((const float4*)vr)[q + j];
            wnd[4 * j + 0] = t.x;
            wnd[4 * j + 1] = t.y;
            wnd[4 * j + 2] = t.z;
            wnd[4 * j + 3] = t.w;
        }
        vfloat4 res;
#pragma unroll
        for (int j = 0; j < 4; ++j) {
            res[j] =
                CW0 * (wnd[j + 2] + wnd[j + 14]) +
                CW1 * (wnd[j + 5] + wnd[j + 11]) +
                CW2 * wnd[j + 8];
        }
        __builtin_nontemporal_store(res, &((vfloat4*)ob)[r * ROWQ + q]);
    }
}

extern "C" void kernel_launch(void* const* d_in, const int* in_sizes, int n_in,
                              void* d_out, int out_size, void* d_ws, size_t ws_size,
                              hipStream_t stream) {
    const float* x = (const float*)d_in[0];
    float* out = (float*)d_out;
    gauss_blur_fused<<<dim3(NBLK), dim3(NT), 0, stream>>>(x, out);
}